// Round 1
// baseline (552.746 us; speedup 1.0000x reference)
//
#include <hip/hip_runtime.h>
#include <hip/hip_bf16.h>
#include <math.h>

#define BS 256
#define J  50
#define O  50
#define MM 50
#define E  64
#define NSEQ (BS*J)     // 12800
#define G4 (4*E)        // 256
#define DD 192          // 3*E

// persistent device scratch (fully rewritten every call)
__device__ float g_u[G4], g_v[G4], g_w[G4];
__device__ float g_hc[DD];
__device__ float g_wproj[8];
__device__ float g_cproj;
__device__ float g_je[NSEQ * E];

__device__ __forceinline__ float sigm(float x) {
    return __fdividef(1.f, 1.f + __expf(-x));
}
__device__ __forceinline__ float ftanh(float x) {
    float ax = fabsf(x);
    float t  = __expf(-2.f * ax);
    float r  = __fdividef(1.f - t, 1.f + t);
    return copysignf(r, x);
}

// ---------------------------------------------------------------------------
// Kernel A: precompute collapsed input projection (u,v,w), Set2Set constant
// hidden h_const, and the attention-logit projection (wproj, cproj).
// ---------------------------------------------------------------------------
__global__ __launch_bounds__(256) void precompute_kernel(
    const float* __restrict__ Wmac, const float* __restrict__ bmac,
    const float* __restrict__ Wjt,  const float* __restrict__ bjt,
    const float* __restrict__ Wih,  const float* __restrict__ bih,
    const float* __restrict__ bhh,
    const float* __restrict__ Wdyn, const float* __restrict__ bdyn,
    const float* __restrict__ bih2, const float* __restrict__ bhh2)
{
    __shared__ float s_hc[DD];
    const int g = threadIdx.x;  // 0..255

    // u[g] = sum_e Wih[g,e]*Wmac[e];  v[g] = sum_e Wih[g,64+e]*Wjt[e]
    // w[g] = sum_e Wih[g,e]*bmac[e] + Wih[g,64+e]*bjt[e] + bih[g] + bhh[g]
    {
        const float* row = &Wih[g * (2 * E)];
        float u = 0.f, v = 0.f, w = 0.f;
        #pragma unroll 8
        for (int e = 0; e < E; ++e) {
            float w0 = row[e], w1 = row[E + e];
            u = fmaf(w0, Wmac[e], u);
            v = fmaf(w1, Wjt[e], v);
            w = fmaf(w0, bmac[e], fmaf(w1, bjt[e], w));
        }
        g_u[g] = u;
        g_v[g] = v;
        g_w[g] = w + bih[g] + bhh[g];
    }

    // Set2Set with q_star=h=c=0: gates = bih2+bhh2 (constant)
    if (g < DD) {
        float gi = bih2[g]          + bhh2[g];
        float gg = bih2[2 * DD + g] + bhh2[2 * DD + g];
        float go = bih2[3 * DD + g] + bhh2[3 * DD + g];
        float c  = sigm(gi) * ftanh(gg);   // sig(f)*c0 = 0
        float h  = sigm(go) * ftanh(c);
        s_hc[g] = h;
        g_hc[g] = h;
    }
    __syncthreads();

    // e_dyn = feats . wproj + cproj  where wproj[f] = sum_d hc[64+d]*Wdyn[d,f]
    if (g < 8) {
        float s = 0.f;
        if (g < 7) {
            for (int d = 0; d < 2 * E; ++d) s = fmaf(s_hc[E + d], Wdyn[d * 7 + g], s);
        }
        g_wproj[g] = s;
    }
    if (g == 8) {
        float s = 0.f;
        for (int d = 0; d < 2 * E; ++d) s = fmaf(s_hc[E + d], bdyn[d], s);
        g_cproj = s;
    }
}

// ---------------------------------------------------------------------------
// Kernel B: the LSTM. One wave (64 lanes) per sequence; lane e owns hidden
// unit e and its 4 gate rows of Whh (256 VGPRs). h exchanged via 256B LDS,
// read as uniform-address float4 broadcasts. Early exit at t* = O-job_state.
// ---------------------------------------------------------------------------
__global__ __launch_bounds__(64, 1) void lstm_kernel(
    const float* __restrict__ job_times,   // [BS*J, O]
    const int*   __restrict__ precedence,  // [BS*J, M]
    const int*   __restrict__ job_state,   // [BS*J]
    const float* __restrict__ Whh)         // [256, 64]
{
    __shared__ float4 h4[16];  // h as 16 float4
    const int lane = threadIdx.x;

    // Whh rows for gates lane, 64+lane, 128+lane, 192+lane -> registers
    float4 wi[16], wf[16], wg[16], wo[16];
    {
        const float4* W4 = reinterpret_cast<const float4*>(Whh);
        #pragma unroll
        for (int q = 0; q < 16; ++q) wi[q] = W4[(0 * E + lane) * 16 + q];
        #pragma unroll
        for (int q = 0; q < 16; ++q) wf[q] = W4[(1 * E + lane) * 16 + q];
        #pragma unroll
        for (int q = 0; q < 16; ++q) wg[q] = W4[(2 * E + lane) * 16 + q];
        #pragma unroll
        for (int q = 0; q < 16; ++q) wo[q] = W4[(3 * E + lane) * 16 + q];
    }
    const float ui = g_u[lane], uf = g_u[E + lane], ug = g_u[2 * E + lane], uo = g_u[3 * E + lane];
    const float vi = g_v[lane], vf = g_v[E + lane], vg = g_v[2 * E + lane], vo = g_v[3 * E + lane];
    const float wwi = g_w[lane], wwf = g_w[E + lane], wwg = g_w[2 * E + lane], wwo = g_w[3 * E + lane];

    for (int s = blockIdx.x; s < NSEQ; s += gridDim.x) {
        const int js   = job_state[s];
        const int tmax = O - js;           // steps t = 0..tmax
        const int*   pr = &precedence[s * MM];
        const float* jt = &job_times[s * O];

        float h, c;
        // ---- peeled t = 0 (h = c = 0; reversed input index o = O = pad) ----
        {
            const float pv = (float)MM;    // pad machine id
            // jv = 0
            float ai = fmaf(pv, ui, wwi);
            float af = fmaf(pv, uf, wwf);
            float ag = fmaf(pv, ug, wwg);
            float ao = fmaf(pv, uo, wwo);
            float si = sigm(ai), sf = sigm(af), so = sigm(ao);
            float tg = ftanh(ag);
            (void)sf;
            c = si * tg;                   // sf*c0 = 0
            h = so * ftanh(c);
            __syncthreads();
            reinterpret_cast<float*>(h4)[lane] = h;
            __syncthreads();
        }
        // ---- steps t = 1..tmax (original op index o = O - t in [0, O-1]) ----
        for (int t = 1; t <= tmax; ++t) {
            const int o = O - t;
            const float pv = (float)pr[o];
            const float jv = jt[o];
            float ai = fmaf(pv, ui, fmaf(jv, vi, wwi));
            float af = fmaf(pv, uf, fmaf(jv, vf, wwf));
            float ag = fmaf(pv, ug, fmaf(jv, vg, wwg));
            float ao = fmaf(pv, uo, fmaf(jv, vo, wwo));
            #pragma unroll
            for (int q = 0; q < 16; ++q) {
                const float4 hv = h4[q];
                ai = fmaf(hv.x, wi[q].x, ai); af = fmaf(hv.x, wf[q].x, af);
                ag = fmaf(hv.x, wg[q].x, ag); ao = fmaf(hv.x, wo[q].x, ao);
                ai = fmaf(hv.y, wi[q].y, ai); af = fmaf(hv.y, wf[q].y, af);
                ag = fmaf(hv.y, wg[q].y, ag); ao = fmaf(hv.y, wo[q].y, ao);
                ai = fmaf(hv.z, wi[q].z, ai); af = fmaf(hv.z, wf[q].z, af);
                ag = fmaf(hv.z, wg[q].z, ag); ao = fmaf(hv.z, wo[q].z, ao);
                ai = fmaf(hv.w, wi[q].w, ai); af = fmaf(hv.w, wf[q].w, af);
                ag = fmaf(hv.w, wg[q].w, ag); ao = fmaf(hv.w, wo[q].w, ao);
            }
            float si = sigm(ai), sf = sigm(af), so = sigm(ao);
            float tg = ftanh(ag);
            c = fmaf(sf, c, si * tg);
            h = so * ftanh(c);
            __syncthreads();               // all lanes done reading old h
            reinterpret_cast<float*>(h4)[lane] = h;
            __syncthreads();               // new h visible
        }
        g_je[s * E + lane] = h;
    }
}

// ---------------------------------------------------------------------------
// Kernel C: dynamic features + attention + output assembly. One block per
// batch element.
// ---------------------------------------------------------------------------
__global__ __launch_bounds__(256) void finalize_kernel(
    const float* __restrict__ job_times, const int* __restrict__ precedence,
    const int* __restrict__ job_state,   const float* __restrict__ jest,
    const float* __restrict__ macut,     const float* __restrict__ mksp,
    const float* __restrict__ Wdyn,      const float* __restrict__ bdyn,
    float* __restrict__ out)
{
    const int b   = blockIdx.x;
    const int tid = threadIdx.x;

    __shared__ float rows[J][MM + 2];  // ordered work per (job, machine)
    __shared__ float twm[MM + 1];
    __shared__ float feats[J][8];
    __shared__ float aw[J];
    __shared__ float fbar[8];

    for (int i = tid; i < J * (MM + 2); i += 256)
        reinterpret_cast<float*>(rows)[i] = 0.f;
    __syncthreads();

    // deterministic scatter: rows[j][precedence[b,j,o]] = job_times[b,j,o]
    if (tid < J) {
        const int j = tid;
        const int*   pr = &precedence[(b * J + j) * MM];
        const float* jt = &job_times[(b * J + j) * O];
        for (int o = 0; o < O; ++o) rows[j][pr[o]] = jt[o];
    }
    __syncthreads();

    // twm[p] = sum_j rows[j][p]   (col MM stays 0)
    if (tid <= MM) {
        float s = 0.f;
        for (int j = 0; j < J; ++j) s += rows[j][tid];
        twm[tid] = s;
    }
    __syncthreads();

    // per-job features + attention logit
    if (tid < J) {
        const int j  = tid;
        const int js = job_state[b * J + j];
        const float* jt = &job_times[(b * J + j) * O];
        float jpt = (js < O) ? jt[js] : 0.f;
        float jst = jest[b * J + j];
        float twr = 0.f;
        for (int o = js; o < O; ++o) twr += jt[o];
        int   mac = (js < O) ? precedence[(b * J + j) * MM + js] : MM;
        float mu  = (mac < MM) ? macut[b * MM + mac] : 0.f;
        float trm = twm[mac] - mu;
        float cm  = mksp[b];
        float f0 = jpt, f1 = jst, f2 = jst + jpt, f3 = twr, f4 = mu, f5 = trm, f6 = cm;
        feats[j][0] = f0; feats[j][1] = f1; feats[j][2] = f2; feats[j][3] = f3;
        feats[j][4] = f4; feats[j][5] = f5; feats[j][6] = f6; feats[j][7] = 0.f;

        float e = g_cproj;
        e = fmaf(f0, g_wproj[0], e); e = fmaf(f1, g_wproj[1], e);
        e = fmaf(f2, g_wproj[2], e); e = fmaf(f3, g_wproj[3], e);
        e = fmaf(f4, g_wproj[4], e); e = fmaf(f5, g_wproj[5], e);
        e = fmaf(f6, g_wproj[6], e);
        const float* je = &g_je[(b * J + j) * E];
        #pragma unroll 8
        for (int d = 0; d < E; ++d) e = fmaf(je[d], g_hc[d], e);
        aw[j] = e;
    }
    __syncthreads();

    // softmax over j (serial in thread 0; tiny)
    if (tid == 0) {
        float mx = aw[0];
        for (int j = 1; j < J; ++j) mx = fmaxf(mx, aw[j]);
        float sum = 0.f;
        for (int j = 0; j < J; ++j) { float ex = __expf(aw[j] - mx); aw[j] = ex; sum += ex; }
        float inv = __fdividef(1.f, sum);
        for (int j = 0; j < J; ++j) aw[j] *= inv;
    }
    __syncthreads();

    float* ob = out + b * (2 * DD);  // 384 per batch

    // fbar[f] = sum_j a[j]*feats[j][f]
    if (tid < 8) {
        float s = 0.f;
        for (int j = 0; j < J; ++j) s = fmaf(aw[j], feats[j][tid], s);
        fbar[tid] = s;
    }
    // out[b, 0:192] = h_const
    if (tid < DD) ob[tid] = g_hc[tid];
    // out[b, 192:256] = sum_j a[j]*je[b,j,:]
    if (tid >= 64 && tid < 128) {
        const int d = tid - 64;
        float s = 0.f;
        for (int j = 0; j < J; ++j) s = fmaf(aw[j], g_je[(b * J + j) * E + d], s);
        ob[DD + d] = s;
    }
    __syncthreads();
    // out[b, 256:384] = fbar @ Wdyn.T + bdyn
    if (tid < 2 * E) {
        float s = bdyn[tid];
        const float* wd = &Wdyn[tid * 7];
        #pragma unroll
        for (int f = 0; f < 7; ++f) s = fmaf(fbar[f], wd[f], s);
        ob[DD + E + tid] = s;
    }
}

// ---------------------------------------------------------------------------
extern "C" void kernel_launch(void* const* d_in, const int* in_sizes, int n_in,
                              void* d_out, int out_size, void* d_ws, size_t ws_size,
                              hipStream_t stream)
{
    const float* job_times  = (const float*)d_in[0];
    const int*   precedence = (const int*)  d_in[1];
    const int*   job_state  = (const int*)  d_in[2];
    const float* jest       = (const float*)d_in[3];
    const float* macut      = (const float*)d_in[4];
    const float* mksp       = (const float*)d_in[5];
    const float* Wmac       = (const float*)d_in[6];
    const float* bmac       = (const float*)d_in[7];
    const float* Wjt        = (const float*)d_in[8];
    const float* bjt        = (const float*)d_in[9];
    const float* Wih        = (const float*)d_in[10];
    const float* Whh        = (const float*)d_in[11];
    const float* bih        = (const float*)d_in[12];
    const float* bhh        = (const float*)d_in[13];
    const float* Wdyn       = (const float*)d_in[14];
    const float* bdyn       = (const float*)d_in[15];
    // d_in[16] Wih2, d_in[17] Whh2 are mathematically unused (q_star = h = 0)
    const float* bih2       = (const float*)d_in[18];
    const float* bhh2       = (const float*)d_in[19];

    precompute_kernel<<<1, 256, 0, stream>>>(Wmac, bmac, Wjt, bjt, Wih, bih, bhh,
                                             Wdyn, bdyn, bih2, bhh2);
    lstm_kernel<<<2048, 64, 0, stream>>>(job_times, precedence, job_state, Whh);
    finalize_kernel<<<BS, 256, 0, stream>>>(job_times, precedence, job_state, jest,
                                            macut, mksp, Wdyn, bdyn, (float*)d_out);
}

// Round 3
// 218.489 us; speedup vs baseline: 2.5299x; 2.5299x over previous
//
#include <hip/hip_runtime.h>
#include <hip/hip_bf16.h>
#include <math.h>

#define BS 256
#define J  50
#define O  50
#define MM 50
#define E  64
#define NSEQ (BS*J)     // 12800
#define G4 (4*E)        // 256
#define DD 192          // 3*E

typedef _Float16 half2v __attribute__((ext_vector_type(2)));

// persistent device scratch (fully rewritten every call)
__device__ float g_u[G4], g_v[G4], g_w[G4];
__device__ float g_hc[DD];
__device__ float g_wproj[8];
__device__ float g_cproj;
__device__ float g_je[NSEQ * E];

__device__ __forceinline__ float sigm(float x) {
    return __fdividef(1.f, 1.f + __expf(-x));
}
__device__ __forceinline__ float ftanh(float x) {
    float ax = fabsf(x);
    float t  = __expf(-2.f * ax);
    float r  = __fdividef(1.f - t, 1.f + t);
    return copysignf(r, x);
}

#if __has_builtin(__builtin_amdgcn_fdot2)
__device__ __forceinline__ float DOT2(half2v a, half2v b, float c) {
    return __builtin_amdgcn_fdot2(a, b, c, false);
}
#else
__device__ __forceinline__ float DOT2(half2v a, half2v b, float c) {
    return fmaf((float)a[0], (float)b[0], fmaf((float)a[1], (float)b[1], c));
}
#endif

__device__ __forceinline__ half2v PK(float a, float b) {
#if __has_builtin(__builtin_amdgcn_cvt_pkrtz)
    auto t = __builtin_amdgcn_cvt_pkrtz(a, b);   // __fp16 ext_vector_type(2)
    return __builtin_bit_cast(half2v, t);
#else
    half2v r; r[0] = (_Float16)a; r[1] = (_Float16)b; return r;
#endif
}

// ---------------------------------------------------------------------------
// Kernel A: precompute collapsed input projection (u,v,w), Set2Set constant
// hidden h_const, attention-logit projection (wproj, cproj); reset work queue.
// ---------------------------------------------------------------------------
__global__ __launch_bounds__(256) void precompute_kernel(
    const float* __restrict__ Wmac, const float* __restrict__ bmac,
    const float* __restrict__ Wjt,  const float* __restrict__ bjt,
    const float* __restrict__ Wih,  const float* __restrict__ bih,
    const float* __restrict__ bhh,
    const float* __restrict__ Wdyn, const float* __restrict__ bdyn,
    const float* __restrict__ bih2, const float* __restrict__ bhh2,
    unsigned int* __restrict__ cnt)
{
    __shared__ float s_hc[DD];
    const int g = threadIdx.x;  // 0..255

    if (g == 0) *cnt = 0u;  // reset LSTM work queue every call

    {
        const float* row = &Wih[g * (2 * E)];
        float u = 0.f, v = 0.f, w = 0.f;
        #pragma unroll 8
        for (int e = 0; e < E; ++e) {
            float w0 = row[e], w1 = row[E + e];
            u = fmaf(w0, Wmac[e], u);
            v = fmaf(w1, Wjt[e], v);
            w = fmaf(w0, bmac[e], fmaf(w1, bjt[e], w));
        }
        g_u[g] = u;
        g_v[g] = v;
        g_w[g] = w + bih[g] + bhh[g];
    }

    // Set2Set with q_star=h=c=0: gates = bih2+bhh2 (constant)
    if (g < DD) {
        float gi = bih2[g]          + bhh2[g];
        float gg = bih2[2 * DD + g] + bhh2[2 * DD + g];
        float go = bih2[3 * DD + g] + bhh2[3 * DD + g];
        float c  = sigm(gi) * ftanh(gg);
        float h  = sigm(go) * ftanh(c);
        s_hc[g] = h;
        g_hc[g] = h;
    }
    __syncthreads();

    if (g < 8) {
        float s = 0.f;
        if (g < 7) {
            for (int d = 0; d < 2 * E; ++d) s = fmaf(s_hc[E + d], Wdyn[d * 7 + g], s);
        }
        g_wproj[g] = s;
    }
    if (g == 8) {
        float s = 0.f;
        for (int d = 0; d < 2 * E; ++d) s = fmaf(s_hc[E + d], bdyn[d], s);
        g_cproj = s;
    }
}

// ---------------------------------------------------------------------------
// Kernel B: the LSTM. One wave per sequence (dynamic work queue). Lane e owns
// hidden unit e; Whh rows for its 4 gates live in VGPRs as packed f16 pairs
// (128 VGPRs -> no spill). Recurrent matmul via v_dot2_f32_f16 (2 MAC/inst).
// h exchanged via a 128 B LDS buffer of f16, read as uniform 16B broadcasts.
// ---------------------------------------------------------------------------
struct alignas(16) H8 { half2v p[4]; };  // 8 halves = 4 half2

__global__ __launch_bounds__(64, 1) void lstm_kernel(
    const float* __restrict__ job_times,   // [BS*J, O]
    const int*   __restrict__ precedence,  // [BS*J, M]
    const int*   __restrict__ job_state,   // [BS*J]
    const float* __restrict__ Whh,         // [256, 64]
    unsigned int* __restrict__ cnt)
{
    __shared__ alignas(16) _Float16 h16[E];
    __shared__ unsigned int s_next;
    const int lane = threadIdx.x;

    // pack Whh rows {lane, 64+lane, 128+lane, 192+lane} -> f16x2, 128 VGPRs
    half2v w[4][32];
    {
        const float4* W4 = reinterpret_cast<const float4*>(Whh);
        #pragma unroll
        for (int gi = 0; gi < 4; ++gi) {
            #pragma unroll
            for (int q = 0; q < 16; ++q) {
                float4 v = W4[(gi * E + lane) * 16 + q];
                w[gi][2 * q]     = PK(v.x, v.y);
                w[gi][2 * q + 1] = PK(v.z, v.w);
            }
        }
    }
    const float ui = g_u[lane], uf = g_u[E + lane], ug = g_u[2 * E + lane], uo = g_u[3 * E + lane];
    const float vi = g_v[lane], vf = g_v[E + lane], vg = g_v[2 * E + lane], vo = g_v[3 * E + lane];
    const float wwi = g_w[lane], wwf = g_w[E + lane], wwg = g_w[2 * E + lane], wwo = g_w[3 * E + lane];

    const H8* h8 = reinterpret_cast<const H8*>(h16);

    for (;;) {
        if (lane == 0) s_next = atomicAdd(cnt, 1u);
        __syncthreads();
        const unsigned s = s_next;
        if (s >= NSEQ) break;

        const int js   = job_state[s];
        const int tmax = O - js;           // steps t = 0..tmax
        const int*   pr = &precedence[s * MM];
        const float* jt = &job_times[s * O];

        float h, c;
        // ---- peeled t = 0 (h = c = 0; reversed input index o = O = pad) ----
        {
            const float pv = (float)MM;    // pad machine id; jv = 0
            float ai = fmaf(pv, ui, wwi);
            float ag = fmaf(pv, ug, wwg);
            float ao = fmaf(pv, uo, wwo);
            float si = sigm(ai), so = sigm(ao);
            float tg = ftanh(ag);
            c = si * tg;                   // sigm(f)*c0 = 0
            h = so * ftanh(c);
            h16[lane] = (_Float16)h;
            __syncthreads();
        }
        // prefetch step-1 inputs (uniform scalar loads)
        float pv_n = 0.f, jv_n = 0.f;
        if (tmax >= 1) { pv_n = (float)pr[O - 1]; jv_n = jt[O - 1]; }

        // ---- steps t = 1..tmax (original op index o = O - t) ----
        for (int t = 1; t <= tmax; ++t) {
            const float pv = pv_n, jv = jv_n;
            if (t < tmax) {                // prefetch next step under the dots
                const int o = O - t - 1;
                pv_n = (float)pr[o];
                jv_n = jt[o];
            }
            float ai = fmaf(pv, ui, fmaf(jv, vi, wwi));
            float af = fmaf(pv, uf, fmaf(jv, vf, wwf));
            float ag = fmaf(pv, ug, fmaf(jv, vg, wwg));
            float ao = fmaf(pv, uo, fmaf(jv, vo, wwo));
            #pragma unroll
            for (int q = 0; q < 8; ++q) {
                const H8 hh = h8[q];       // ds_read_b128, uniform broadcast
                #pragma unroll
                for (int r = 0; r < 4; ++r) {
                    const half2v hv = hh.p[r];
                    const int k = q * 4 + r;
                    ai = DOT2(w[0][k], hv, ai);
                    af = DOT2(w[1][k], hv, af);
                    ag = DOT2(w[2][k], hv, ag);
                    ao = DOT2(w[3][k], hv, ao);
                }
            }
            float si = sigm(ai), sf = sigm(af), so = sigm(ao);
            float tg = ftanh(ag);
            c = fmaf(sf, c, si * tg);
            h = so * ftanh(c);
            __syncthreads();               // all lanes done reading old h
            h16[lane] = (_Float16)h;
            __syncthreads();               // new h visible
        }
        g_je[s * E + lane] = h;
    }
}

// ---------------------------------------------------------------------------
// Kernel C: dynamic features + attention + output assembly. One block per
// batch element.
// ---------------------------------------------------------------------------
__global__ __launch_bounds__(256) void finalize_kernel(
    const float* __restrict__ job_times, const int* __restrict__ precedence,
    const int* __restrict__ job_state,   const float* __restrict__ jest,
    const float* __restrict__ macut,     const float* __restrict__ mksp,
    const float* __restrict__ Wdyn,      const float* __restrict__ bdyn,
    float* __restrict__ out)
{
    const int b   = blockIdx.x;
    const int tid = threadIdx.x;

    __shared__ float rows[J][MM + 2];  // ordered work per (job, machine)
    __shared__ float twm[MM + 1];
    __shared__ float feats[J][8];
    __shared__ float aw[J];
    __shared__ float fbar[8];

    for (int i = tid; i < J * (MM + 2); i += 256)
        reinterpret_cast<float*>(rows)[i] = 0.f;
    __syncthreads();

    if (tid < J) {
        const int j = tid;
        const int*   pr = &precedence[(b * J + j) * MM];
        const float* jt = &job_times[(b * J + j) * O];
        for (int o = 0; o < O; ++o) rows[j][pr[o]] = jt[o];
    }
    __syncthreads();

    if (tid <= MM) {
        float s = 0.f;
        for (int j = 0; j < J; ++j) s += rows[j][tid];
        twm[tid] = s;
    }
    __syncthreads();

    if (tid < J) {
        const int j  = tid;
        const int js = job_state[b * J + j];
        const float* jt = &job_times[(b * J + j) * O];
        float jpt = (js < O) ? jt[js] : 0.f;
        float jst = jest[b * J + j];
        float twr = 0.f;
        for (int o = js; o < O; ++o) twr += jt[o];
        int   mac = (js < O) ? precedence[(b * J + j) * MM + js] : MM;
        float mu  = (mac < MM) ? macut[b * MM + mac] : 0.f;
        float trm = twm[mac] - mu;
        float cm  = mksp[b];
        float f0 = jpt, f1 = jst, f2 = jst + jpt, f3 = twr, f4 = mu, f5 = trm, f6 = cm;
        feats[j][0] = f0; feats[j][1] = f1; feats[j][2] = f2; feats[j][3] = f3;
        feats[j][4] = f4; feats[j][5] = f5; feats[j][6] = f6; feats[j][7] = 0.f;

        float e = g_cproj;
        e = fmaf(f0, g_wproj[0], e); e = fmaf(f1, g_wproj[1], e);
        e = fmaf(f2, g_wproj[2], e); e = fmaf(f3, g_wproj[3], e);
        e = fmaf(f4, g_wproj[4], e); e = fmaf(f5, g_wproj[5], e);
        e = fmaf(f6, g_wproj[6], e);
        const float* je = &g_je[(b * J + j) * E];
        #pragma unroll 8
        for (int d = 0; d < E; ++d) e = fmaf(je[d], g_hc[d], e);
        aw[j] = e;
    }
    __syncthreads();

    if (tid == 0) {
        float mx = aw[0];
        for (int j = 1; j < J; ++j) mx = fmaxf(mx, aw[j]);
        float sum = 0.f;
        for (int j = 0; j < J; ++j) { float ex = __expf(aw[j] - mx); aw[j] = ex; sum += ex; }
        float inv = __fdividef(1.f, sum);
        for (int j = 0; j < J; ++j) aw[j] *= inv;
    }
    __syncthreads();

    float* ob = out + b * (2 * DD);  // 384 per batch

    if (tid < 8) {
        float s = 0.f;
        for (int j = 0; j < J; ++j) s = fmaf(aw[j], feats[j][tid], s);
        fbar[tid] = s;
    }
    if (tid < DD) ob[tid] = g_hc[tid];
    if (tid >= 64 && tid < 128) {
        const int d = tid - 64;
        float s = 0.f;
        for (int j = 0; j < J; ++j) s = fmaf(aw[j], g_je[(b * J + j) * E + d], s);
        ob[DD + d] = s;
    }
    __syncthreads();
    if (tid < 2 * E) {
        float s = bdyn[tid];
        const float* wd = &Wdyn[tid * 7];
        #pragma unroll
        for (int f = 0; f < 7; ++f) s = fmaf(fbar[f], wd[f], s);
        ob[DD + E + tid] = s;
    }
}

// ---------------------------------------------------------------------------
extern "C" void kernel_launch(void* const* d_in, const int* in_sizes, int n_in,
                              void* d_out, int out_size, void* d_ws, size_t ws_size,
                              hipStream_t stream)
{
    const float* job_times  = (const float*)d_in[0];
    const int*   precedence = (const int*)  d_in[1];
    const int*   job_state  = (const int*)  d_in[2];
    const float* jest       = (const float*)d_in[3];
    const float* macut      = (const float*)d_in[4];
    const float* mksp       = (const float*)d_in[5];
    const float* Wmac       = (const float*)d_in[6];
    const float* bmac       = (const float*)d_in[7];
    const float* Wjt        = (const float*)d_in[8];
    const float* bjt        = (const float*)d_in[9];
    const float* Wih        = (const float*)d_in[10];
    const float* Whh        = (const float*)d_in[11];
    const float* bih        = (const float*)d_in[12];
    const float* bhh        = (const float*)d_in[13];
    const float* Wdyn       = (const float*)d_in[14];
    const float* bdyn       = (const float*)d_in[15];
    // d_in[16] Wih2, d_in[17] Whh2 are mathematically unused (q_star = h = 0)
    const float* bih2       = (const float*)d_in[18];
    const float* bhh2       = (const float*)d_in[19];

    unsigned int* cnt = (unsigned int*)d_ws;

    precompute_kernel<<<1, 256, 0, stream>>>(Wmac, bmac, Wjt, bjt, Wih, bih, bhh,
                                             Wdyn, bdyn, bih2, bhh2, cnt);
    lstm_kernel<<<2048, 64, 0, stream>>>(job_times, precedence, job_state, Whh, cnt);
    finalize_kernel<<<BS, 256, 0, stream>>>(job_times, precedence, job_state, jest,
                                            macut, mksp, Wdyn, bdyn, (float*)d_out);
}

// Round 4
// 212.486 us; speedup vs baseline: 2.6013x; 1.0283x over previous
//
#include <hip/hip_runtime.h>
#include <hip/hip_bf16.h>
#include <math.h>

#define BS 256
#define J  50
#define O  50
#define MM 50
#define E  64
#define NSEQ (BS*J)     // 12800
#define G4 (4*E)        // 256
#define DD 192          // 3*E

typedef _Float16 half2v __attribute__((ext_vector_type(2)));

// persistent device scratch (fully rewritten every call)
__device__ float g_u[G4], g_v[G4], g_w[G4];
__device__ float g_h0[E], g_c0[E];
__device__ float g_hc[DD];
__device__ float g_wproj[8];
__device__ float g_cproj;
__device__ float g_je[NSEQ * E];

__device__ __forceinline__ float sigm(float x) {
    return __fdividef(1.f, 1.f + __expf(-x));
}
__device__ __forceinline__ float ftanh(float x) {
    float ax = fabsf(x);
    float t  = __expf(-2.f * ax);
    float r  = __fdividef(1.f - t, 1.f + t);
    return copysignf(r, x);
}

#if __has_builtin(__builtin_amdgcn_fdot2)
__device__ __forceinline__ float DOT2(half2v a, half2v b, float c) {
    return __builtin_amdgcn_fdot2(a, b, c, false);
}
#else
__device__ __forceinline__ float DOT2(half2v a, half2v b, float c) {
    return fmaf((float)a[0], (float)b[0], fmaf((float)a[1], (float)b[1], c));
}
#endif

__device__ __forceinline__ half2v PK(float a, float b) {
#if __has_builtin(__builtin_amdgcn_cvt_pkrtz)
    auto t = __builtin_amdgcn_cvt_pkrtz(a, b);   // __fp16 ext_vector_type(2)
    return __builtin_bit_cast(half2v, t);
#else
    half2v r; r[0] = (_Float16)a; r[1] = (_Float16)b; return r;
#endif
}

// ---------------------------------------------------------------------------
// Kernel A: precompute collapsed input projection (u,v,w), the shared first
// LSTM step (h0,c0 — input-independent: pad column pv=M, jv=0), Set2Set
// constant hidden, attention-logit projection; reset work queue.
// ---------------------------------------------------------------------------
__global__ __launch_bounds__(256) void precompute_kernel(
    const float* __restrict__ Wmac, const float* __restrict__ bmac,
    const float* __restrict__ Wjt,  const float* __restrict__ bjt,
    const float* __restrict__ Wih,  const float* __restrict__ bih,
    const float* __restrict__ bhh,
    const float* __restrict__ Wdyn, const float* __restrict__ bdyn,
    const float* __restrict__ bih2, const float* __restrict__ bhh2,
    unsigned int* __restrict__ cnt)
{
    __shared__ float s_hc[DD];
    const int g = threadIdx.x;  // 0..255

    if (g == 0) *cnt = 0u;  // reset LSTM work queue every call

    {
        const float* row = &Wih[g * (2 * E)];
        float u = 0.f, v = 0.f, w = 0.f;
        #pragma unroll 8
        for (int e = 0; e < E; ++e) {
            float w0 = row[e], w1 = row[E + e];
            u = fmaf(w0, Wmac[e], u);
            v = fmaf(w1, Wjt[e], v);
            w = fmaf(w0, bmac[e], fmaf(w1, bjt[e], w));
        }
        g_u[g] = u;
        g_v[g] = v;
        g_w[g] = w + bih[g] + bhh[g];
    }

    // Set2Set with q_star=h=c=0: gates = bih2+bhh2 (constant)
    if (g < DD) {
        float gi = bih2[g]          + bhh2[g];
        float gg = bih2[2 * DD + g] + bhh2[2 * DD + g];
        float go = bih2[3 * DD + g] + bhh2[3 * DD + g];
        float c  = sigm(gi) * ftanh(gg);
        float h  = sigm(go) * ftanh(c);
        s_hc[g] = h;
        g_hc[g] = h;
    }
    __syncthreads();

    // shared t=0 LSTM step: inputs are constants (pv = M, jv = 0), h=c=0
    if (g < E) {
        float ai = fmaf((float)MM, g_u[g],           g_w[g]);
        float ag = fmaf((float)MM, g_u[2 * E + g],   g_w[2 * E + g]);
        float ao = fmaf((float)MM, g_u[3 * E + g],   g_w[3 * E + g]);
        float c0 = sigm(ai) * ftanh(ag);   // sigm(f)*c_prev = 0
        float h0 = sigm(ao) * ftanh(c0);
        g_h0[g] = h0;
        g_c0[g] = c0;
    }

    if (g < 8) {
        float s = 0.f;
        if (g < 7) {
            for (int d = 0; d < 2 * E; ++d) s = fmaf(s_hc[E + d], Wdyn[d * 7 + g], s);
        }
        g_wproj[g] = s;
    }
    if (g == 8) {
        float s = 0.f;
        for (int d = 0; d < 2 * E; ++d) s = fmaf(s_hc[E + d], bdyn[d], s);
        g_cproj = s;
    }
}

// ---------------------------------------------------------------------------
// Kernel B: the LSTM. TWO waves per sequence, 2 gates per wave:
//   wave0: gates i,f  (Whh rows lane, 64+lane)       -> owns c and h
//   wave1: gates g,o  (Whh rows 128+lane, 192+lane)  -> sends tanh(g), sigm(o)
// Weights: 64 half2 VGPRs/lane (no AGPR pressure) -> 4 waves/SIMD occupancy.
// h exchanged via 128 B LDS f16 buffer read as uniform 16 B broadcasts;
// tg/so exchanged via 512 B float2 buffer. Dynamic work queue over sequences.
// ---------------------------------------------------------------------------
struct alignas(16) H8 { half2v p[4]; };  // 8 halves = 4 half2

__global__ __launch_bounds__(128, 4) void lstm_kernel(
    const float* __restrict__ job_times,   // [BS*J, O]
    const int*   __restrict__ precedence,  // [BS*J, M]
    const int*   __restrict__ job_state,   // [BS*J]
    const float* __restrict__ Whh,         // [256, 64]
    unsigned int* __restrict__ cnt)
{
    __shared__ alignas(16) _Float16 h16[E];
    __shared__ float2 ex[E];
    __shared__ unsigned int s_next;
    const int tid  = threadIdx.x;
    const int lane = tid & 63;
    const int wid  = tid >> 6;             // 0 or 1 (wave-uniform)

    // this wave's two gate rows
    const int g0 = wid * 2 * E + lane;     // wave0: i-row, wave1: g-row
    const int g1 = g0 + E;                 // wave0: f-row, wave1: o-row

    half2v w0[32], w1[32];
    {
        const float4* W4 = reinterpret_cast<const float4*>(Whh);
        #pragma unroll
        for (int q = 0; q < 16; ++q) {
            float4 a = W4[g0 * 16 + q];
            w0[2 * q]     = PK(a.x, a.y);
            w0[2 * q + 1] = PK(a.z, a.w);
        }
        #pragma unroll
        for (int q = 0; q < 16; ++q) {
            float4 a = W4[g1 * 16 + q];
            w1[2 * q]     = PK(a.x, a.y);
            w1[2 * q + 1] = PK(a.z, a.w);
        }
    }
    const float u0 = g_u[g0], u1 = g_u[g1];
    const float v0 = g_v[g0], v1 = g_v[g1];
    const float ww0 = g_w[g0], ww1 = g_w[g1];
    const float h0f = g_h0[lane];
    const float c0f = g_c0[lane];
    const _Float16 h0h = (_Float16)h0f;

    const H8* h8 = reinterpret_cast<const H8*>(h16);

    for (;;) {
        if (wid == 0) h16[lane] = h0h;     // safe: prior seq's readers passed barrier
        if (tid == 0) s_next = atomicAdd(cnt, 1u);
        __syncthreads();                   // h16 ready + s_next visible
        const unsigned s = s_next;
        if (s >= NSEQ) break;

        const int js   = job_state[s];
        const int tmax = O - js;           // remaining steps t = 1..tmax
        const int*   pr = &precedence[s * MM];
        const float* jt = &job_times[s * O];

        float c = c0f;
        float h = h0f;                     // wave0's running hidden (f32)

        float pv_n = 0.f, jv_n = 0.f;
        if (tmax >= 1) { pv_n = (float)pr[O - 1]; jv_n = jt[O - 1]; }

        for (int t = 1; t <= tmax; ++t) {
            const float pv = pv_n, jv = jv_n;
            if (t < tmax) {                // prefetch next step under the dots
                const int o = O - t - 1;
                pv_n = (float)pr[o];
                jv_n = jt[o];
            }
            float a0 = fmaf(pv, u0, fmaf(jv, v0, ww0));
            float a1 = fmaf(pv, u1, fmaf(jv, v1, ww1));
            #pragma unroll
            for (int q = 0; q < 8; ++q) {
                const H8 hh = h8[q];       // ds_read_b128, uniform broadcast
                #pragma unroll
                for (int r = 0; r < 4; ++r) {
                    const half2v hv = hh.p[r];
                    const int k = q * 4 + r;
                    a0 = DOT2(w0[k], hv, a0);
                    a1 = DOT2(w1[k], hv, a1);
                }
            }
            float si = 0.f, sf = 0.f;
            if (wid == 1) {
                ex[lane] = make_float2(ftanh(a0), sigm(a1));   // tg, so
            } else {
                si = sigm(a0);
                sf = sigm(a1);
            }
            __syncthreads();               // ex ready; everyone done reading h16
            if (wid == 0) {
                const float2 e2 = ex[lane];
                c = fmaf(sf, c, si * e2.x);
                h = e2.y * ftanh(c);
                h16[lane] = (_Float16)h;
            }
            __syncthreads();               // new h visible to both waves
        }
        if (wid == 0) g_je[s * E + lane] = h;
    }
}

// ---------------------------------------------------------------------------
// Kernel C: dynamic features + attention + output assembly. One block per
// batch element.
// ---------------------------------------------------------------------------
__global__ __launch_bounds__(256) void finalize_kernel(
    const float* __restrict__ job_times, const int* __restrict__ precedence,
    const int* __restrict__ job_state,   const float* __restrict__ jest,
    const float* __restrict__ macut,     const float* __restrict__ mksp,
    const float* __restrict__ Wdyn,      const float* __restrict__ bdyn,
    float* __restrict__ out)
{
    const int b   = blockIdx.x;
    const int tid = threadIdx.x;

    __shared__ float rows[J][MM + 2];  // ordered work per (job, machine)
    __shared__ float twm[MM + 1];
    __shared__ float feats[J][8];
    __shared__ float aw[J];
    __shared__ float fbar[8];

    for (int i = tid; i < J * (MM + 2); i += 256)
        reinterpret_cast<float*>(rows)[i] = 0.f;
    __syncthreads();

    if (tid < J) {
        const int j = tid;
        const int*   pr = &precedence[(b * J + j) * MM];
        const float* jt = &job_times[(b * J + j) * O];
        for (int o = 0; o < O; ++o) rows[j][pr[o]] = jt[o];
    }
    __syncthreads();

    if (tid <= MM) {
        float s = 0.f;
        for (int j = 0; j < J; ++j) s += rows[j][tid];
        twm[tid] = s;
    }
    __syncthreads();

    if (tid < J) {
        const int j  = tid;
        const int js = job_state[b * J + j];
        const float* jt = &job_times[(b * J + j) * O];
        float jpt = (js < O) ? jt[js] : 0.f;
        float jst = jest[b * J + j];
        float twr = 0.f;
        for (int o = js; o < O; ++o) twr += jt[o];
        int   mac = (js < O) ? precedence[(b * J + j) * MM + js] : MM;
        float mu  = (mac < MM) ? macut[b * MM + mac] : 0.f;
        float trm = twm[mac] - mu;
        float cm  = mksp[b];
        float f0 = jpt, f1 = jst, f2 = jst + jpt, f3 = twr, f4 = mu, f5 = trm, f6 = cm;
        feats[j][0] = f0; feats[j][1] = f1; feats[j][2] = f2; feats[j][3] = f3;
        feats[j][4] = f4; feats[j][5] = f5; feats[j][6] = f6; feats[j][7] = 0.f;

        float e = g_cproj;
        e = fmaf(f0, g_wproj[0], e); e = fmaf(f1, g_wproj[1], e);
        e = fmaf(f2, g_wproj[2], e); e = fmaf(f3, g_wproj[3], e);
        e = fmaf(f4, g_wproj[4], e); e = fmaf(f5, g_wproj[5], e);
        e = fmaf(f6, g_wproj[6], e);
        const float* je = &g_je[(b * J + j) * E];
        #pragma unroll 8
        for (int d = 0; d < E; ++d) e = fmaf(je[d], g_hc[d], e);
        aw[j] = e;
    }
    __syncthreads();

    if (tid == 0) {
        float mx = aw[0];
        for (int j = 1; j < J; ++j) mx = fmaxf(mx, aw[j]);
        float sum = 0.f;
        for (int j = 0; j < J; ++j) { float ex = __expf(aw[j] - mx); aw[j] = ex; sum += ex; }
        float inv = __fdividef(1.f, sum);
        for (int j = 0; j < J; ++j) aw[j] *= inv;
    }
    __syncthreads();

    float* ob = out + b * (2 * DD);  // 384 per batch

    if (tid < 8) {
        float s = 0.f;
        for (int j = 0; j < J; ++j) s = fmaf(aw[j], feats[j][tid], s);
        fbar[tid] = s;
    }
    if (tid < DD) ob[tid] = g_hc[tid];
    if (tid >= 64 && tid < 128) {
        const int d = tid - 64;
        float s = 0.f;
        for (int j = 0; j < J; ++j) s = fmaf(aw[j], g_je[(b * J + j) * E + d], s);
        ob[DD + d] = s;
    }
    __syncthreads();
    if (tid < 2 * E) {
        float s = bdyn[tid];
        const float* wd = &Wdyn[tid * 7];
        #pragma unroll
        for (int f = 0; f < 7; ++f) s = fmaf(fbar[f], wd[f], s);
        ob[DD + E + tid] = s;
    }
}

// ---------------------------------------------------------------------------
extern "C" void kernel_launch(void* const* d_in, const int* in_sizes, int n_in,
                              void* d_out, int out_size, void* d_ws, size_t ws_size,
                              hipStream_t stream)
{
    const float* job_times  = (const float*)d_in[0];
    const int*   precedence = (const int*)  d_in[1];
    const int*   job_state  = (const int*)  d_in[2];
    const float* jest       = (const float*)d_in[3];
    const float* macut      = (const float*)d_in[4];
    const float* mksp       = (const float*)d_in[5];
    const float* Wmac       = (const float*)d_in[6];
    const float* bmac       = (const float*)d_in[7];
    const float* Wjt        = (const float*)d_in[8];
    const float* bjt        = (const float*)d_in[9];
    const float* Wih        = (const float*)d_in[10];
    const float* Whh        = (const float*)d_in[11];
    const float* bih        = (const float*)d_in[12];
    const float* bhh        = (const float*)d_in[13];
    const float* Wdyn       = (const float*)d_in[14];
    const float* bdyn       = (const float*)d_in[15];
    // d_in[16] Wih2, d_in[17] Whh2 are mathematically unused (q_star = h = 0)
    const float* bih2       = (const float*)d_in[18];
    const float* bhh2       = (const float*)d_in[19];

    unsigned int* cnt = (unsigned int*)d_ws;

    precompute_kernel<<<1, 256, 0, stream>>>(Wmac, bmac, Wjt, bjt, Wih, bih, bhh,
                                             Wdyn, bdyn, bih2, bhh2, cnt);
    lstm_kernel<<<2048, 128, 0, stream>>>(job_times, precedence, job_state, Whh, cnt);
    finalize_kernel<<<BS, 256, 0, stream>>>(job_times, precedence, job_state, jest,
                                            macut, mksp, Wdyn, bdyn, (float*)d_out);
}

// Round 6
// 134.781 us; speedup vs baseline: 4.1011x; 1.5765x over previous
//
#include <hip/hip_runtime.h>
#include <hip/hip_bf16.h>
#include <math.h>

#define BS 256
#define J  50
#define O  50
#define MM 50
#define E  64
#define NSEQ (BS*J)     // 12800
#define G4 (4*E)        // 256
#define DD 192          // 3*E
#define NBATCH (NSEQ/32) // 400 batches of 32 sequences
#define KH 80            // extended K: 64 h + pv,jv,1 + zero-pad to 80

typedef _Float16 f16x8 __attribute__((ext_vector_type(8)));
typedef _Float16 half2v __attribute__((ext_vector_type(2)));
typedef float f32x16 __attribute__((ext_vector_type(16)));

// persistent device scratch (fully rewritten every call)
__device__ float g_u[G4], g_v[G4], g_w[G4];
__device__ float g_h0[E], g_c0[E];
__device__ float g_hc[DD];
__device__ float g_wproj[8];
__device__ float g_cproj;
__device__ float g_je[NSEQ * E];
__device__ int   g_idx[NSEQ];

__device__ __forceinline__ float sigm(float x) {
    return __fdividef(1.f, 1.f + __expf(-x));
}
__device__ __forceinline__ float ftanh(float x) {
    // tanh(x) = 2/(1+exp(-2x)) - 1 ; saturates correctly at both ends
    float e = __expf(-2.f * x);
    return fmaf(2.f, __fdividef(1.f, 1.f + e), -1.f);
}

__device__ __forceinline__ half2v PK(float a, float b) {
#if __has_builtin(__builtin_amdgcn_cvt_pkrtz)
    auto t = __builtin_amdgcn_cvt_pkrtz(a, b);   // __fp16 ext_vector_type(2)
    return __builtin_bit_cast(half2v, t);
#else
    half2v r; r[0] = (_Float16)a; r[1] = (_Float16)b; return r;
#endif
}

// ---------------------------------------------------------------------------
// Kernel A: precompute collapsed input projection (u,v,w), shared first LSTM
// step (h0,c0 — input-independent), Set2Set constant hidden, attention-logit
// projection, and a counting sort of sequences by job_state (51 bins) so the
// MFMA kernel can batch 32 near-equal-length sequences per workgroup.
// ---------------------------------------------------------------------------
__global__ __launch_bounds__(256) void precompute_kernel(
    const float* __restrict__ Wmac, const float* __restrict__ bmac,
    const float* __restrict__ Wjt,  const float* __restrict__ bjt,
    const float* __restrict__ Wih,  const float* __restrict__ bih,
    const float* __restrict__ bhh,
    const float* __restrict__ Wdyn, const float* __restrict__ bdyn,
    const float* __restrict__ bih2, const float* __restrict__ bhh2,
    const int*   __restrict__ job_state)
{
    __shared__ float s_hc[DD];
    __shared__ int cnt51[51], cur51[51];
    const int g = threadIdx.x;  // 0..255

    if (g < 51) cnt51[g] = 0;

    {
        const float* row = &Wih[g * (2 * E)];
        float u = 0.f, v = 0.f, w = 0.f;
        #pragma unroll 8
        for (int e = 0; e < E; ++e) {
            float w0 = row[e], w1 = row[E + e];
            u = fmaf(w0, Wmac[e], u);
            v = fmaf(w1, Wjt[e], v);
            w = fmaf(w0, bmac[e], fmaf(w1, bjt[e], w));
        }
        g_u[g] = u;
        g_v[g] = v;
        g_w[g] = w + bih[g] + bhh[g];
    }

    // Set2Set with q_star=h=c=0: gates = bih2+bhh2 (constant)
    if (g < DD) {
        float gi = bih2[g]          + bhh2[g];
        float gg = bih2[2 * DD + g] + bhh2[2 * DD + g];
        float go = bih2[3 * DD + g] + bhh2[3 * DD + g];
        float c  = sigm(gi) * ftanh(gg);
        float h  = sigm(go) * ftanh(c);
        s_hc[g] = h;
        g_hc[g] = h;
    }
    __syncthreads();

    // shared t=0 LSTM step: inputs are constants (pv = M, jv = 0), h=c=0
    if (g < E) {
        float ai = fmaf((float)MM, g_u[g],         g_w[g]);
        float ag = fmaf((float)MM, g_u[2 * E + g], g_w[2 * E + g]);
        float ao = fmaf((float)MM, g_u[3 * E + g], g_w[3 * E + g]);
        float c0 = sigm(ai) * ftanh(ag);
        float h0 = sigm(ao) * ftanh(c0);
        g_h0[g] = h0;
        g_c0[g] = c0;
    }

    if (g < 8) {
        float s = 0.f;
        if (g < 7) {
            for (int d = 0; d < 2 * E; ++d) s = fmaf(s_hc[E + d], Wdyn[d * 7 + g], s);
        }
        g_wproj[g] = s;
    }
    if (g == 8) {
        float s = 0.f;
        for (int d = 0; d < 2 * E; ++d) s = fmaf(s_hc[E + d], bdyn[d], s);
        g_cproj = s;
    }

    // ---- counting sort by job_state (ascending js = descending length) ----
    for (int s = g; s < NSEQ; s += 256)
        atomicAdd(&cnt51[job_state[s]], 1);
    __syncthreads();
    if (g == 0) {
        int run = 0;
        for (int b2 = 0; b2 < 51; ++b2) { cur51[b2] = run; run += cnt51[b2]; }
    }
    __syncthreads();
    for (int s = g; s < NSEQ; s += 256) {
        int pos = atomicAdd(&cur51[job_state[s]], 1);
        g_idx[pos] = s;
    }
}

// ---------------------------------------------------------------------------
// Kernel B: MFMA-batched LSTM. One 512-thread WG per batch of 32 sequences
// (sorted by length). gates[256x32] = G_ext[256x80] @ H_ext[80x32] per step
// via 5x v_mfma_f32_32x32x16_f16 per wave (8 waves = 8 row-tiles).
// G rows are permuted so the D-layout (col=lane&31, row=(reg&3)+8*(reg>>2)
// +4*(lane>>5)) gives each lane all 4 gates of 4 units for one sequence;
// c stays in f32 registers. H rows 64/65/66 = pv,jv,1 fold the input
// projection into the MFMA (K padded to 80).
// SWIZZLE FIX vs r5: the XOR swizzle (halfidx ^= (seq&7)<<3) is only
// bijective within a 64-half-aligned block, so it applies ONLY to the
// h-region k<64. Rows k=64..79 (pv,jv,1,pad) are stored/read UNswizzled
// (the old code indexed up to 64+swz+.. = 122 > 80: out-of-row corruption).
// Per-lane masking by each sequence's own tmax gives exact semantics.
// ---------------------------------------------------------------------------
__global__ __launch_bounds__(512, 4) void lstm_kernel(
    const float* __restrict__ job_times,   // [BS*J, O]
    const int*   __restrict__ precedence,  // [BS*J, M]
    const int*   __restrict__ job_state,   // [BS*J]
    const float* __restrict__ Whh)         // [256, 64]
{
    __shared__ alignas(16) _Float16 H[32 * KH];
    __shared__ int sid_s[32];
    __shared__ int tmx_s[32];
    __shared__ int tmax_sh;

    const int tid  = threadIdx.x;
    const int lane = tid & 63;
    const int wid  = tid >> 6;          // 0..7 row-tile
    const int n    = lane & 31;         // sequence column (D col = lane&31)
    const int hi   = lane >> 5;
    const int swz  = (n & 7) << 3;      // XOR swizzle in half-index units (k<64 only)

    // ---- loop-invariant A fragments (row-permuted G_ext, f16) ----
    // A row_local = lane&31 -> gate q = rl>>3, unit_local = rl&7
    const int rl   = lane & 31;
    const int grow = (rl >> 3) * 64 + 8 * wid + (rl & 7);   // original G row
    f16x8 a[5];
    {
        const float* wr = Whh + grow * 64 + hi * 8;
        #pragma unroll
        for (int kt = 0; kt < 4; ++kt) {
            f16x8 t;
            #pragma unroll
            for (int j = 0; j < 8; ++j) t[j] = (_Float16)wr[kt * 16 + j];
            a[kt] = t;
        }
        f16x8 t;
        #pragma unroll
        for (int j = 0; j < 8; ++j) t[j] = (_Float16)0.f;
        if (hi == 0) {              // k=64,65,66 -> u,v,w columns
            t[0] = (_Float16)g_u[grow];
            t[1] = (_Float16)g_v[grow];
            t[2] = (_Float16)g_w[grow];
        }
        a[4] = t;
    }

    // this lane's 4 units: ub..ub+3
    const int ub = 8 * wid + 4 * hi;
    float c0r[4], h0r[4];
    #pragma unroll
    for (int x = 0; x < 4; ++x) { c0r[x] = g_c0[ub + x]; h0r[x] = g_h0[ub + x]; }

    const int b = blockIdx.x;           // batch id (longest batches first)

    // ---- batch init ----
    if (tid < 32) {
        int s = g_idx[b * 32 + tid];
        sid_s[tid] = s;
        tmx_s[tid] = O - job_state[s];
    }
    {   // zero H (covers rows 67..79 pad and old data)
        int* Hi = (int*)H;
        for (int i = tid; i < 32 * KH / 2; i += 512) Hi[i] = 0;
    }
    __syncthreads();
    if (tid == 0) {
        int m = 0;
        for (int i = 0; i < 32; ++i) m = max(m, tmx_s[i]);
        tmax_sh = m;
    }
    const int sidn  = sid_s[n];
    const int tmaxn = tmx_s[n];
    const int*   prn = precedence + sidn * MM;   // used by wave0 lanes only
    const float* jtn = job_times  + sidn * O;

    float cr[4], hr[4];
    #pragma unroll
    for (int x = 0; x < 4; ++x) { cr[x] = c0r[x]; hr[x] = h0r[x]; }

    {   // write h0 into H (all waves cover all 64 units x 32 cols; k<64 swizzled)
        const int hidx = n * KH + (ub ^ swz);
        *reinterpret_cast<half2v*>(&H[hidx])     = PK(h0r[0], h0r[1]);
        *reinterpret_cast<half2v*>(&H[hidx + 2]) = PK(h0r[2], h0r[3]);
    }
    if (tid < 32) {
        H[n * KH + 66] = (_Float16)1.f;                 // bias row (unswizzled)
        float pv1 = (float)prn[O - 1];
        float jv1 = jtn[O - 1];
        *reinterpret_cast<half2v*>(&H[n * KH + 64]) = PK(pv1, jv1);  // unswizzled
    }
    __syncthreads();
    const int tmaxM = tmax_sh;

    // ---- time loop (lockstep over batch; per-lane masked by tmaxn) ----
    for (int t = 1; t <= tmaxM; ++t) {
        // issue next step's input gathers early (latency hides under MFMA)
        float pv2 = 0.f, jv2 = 0.f;
        if (tid < 32 && t < tmaxM) {
            const int o = O - t - 1;
            pv2 = (float)prn[o];
            jv2 = jtn[o];
        }

        // gates = G_ext @ H_ext  (5 chained MFMA, f32 accumulate)
        f32x16 d;
        #pragma unroll
        for (int j = 0; j < 16; ++j) d[j] = 0.f;
        #pragma unroll
        for (int kt = 0; kt < 5; ++kt) {
            const int kb  = 16 * kt + 8 * hi;          // k base for this lane
            const int off = (kt < 4) ? (kb ^ swz) : kb; // swizzle only k<64
            f16x8 bf = *reinterpret_cast<const f16x8*>(&H[n * KH + off]);
            d = __builtin_amdgcn_mfma_f32_32x32x16_f16(a[kt], bf, d, 0, 0, 0);
        }

        // activations: lane holds gates i,f,g,o for units ub..ub+3, col n
        const bool upd = (t <= tmaxn);
        #pragma unroll
        for (int x = 0; x < 4; ++x) {
            float gi = d[x], gf = d[4 + x], gg = d[8 + x], go = d[12 + x];
            float si = sigm(gi), sf = sigm(gf), so = sigm(go);
            float tg = ftanh(gg);
            float cn = fmaf(sf, cr[x], si * tg);
            float hn = so * ftanh(cn);
            if (upd) { cr[x] = cn; hr[x] = hn; }
        }
        __syncthreads();               // all B-fragment reads of step t done
        if (upd) {
            const int hidx = n * KH + (ub ^ swz);
            *reinterpret_cast<half2v*>(&H[hidx])     = PK(hr[0], hr[1]);
            *reinterpret_cast<half2v*>(&H[hidx + 2]) = PK(hr[2], hr[3]);
        }
        if (tid < 32 && t < tmaxM) {
            *reinterpret_cast<half2v*>(&H[n * KH + 64]) = PK(pv2, jv2);  // unswizzled
        }
        __syncthreads();               // step t+1 inputs visible
    }

    // ---- write final hidden (f32) ----
    {
        float4 v = make_float4(hr[0], hr[1], hr[2], hr[3]);
        *reinterpret_cast<float4*>(&g_je[sidn * E + ub]) = v;
    }
}

// ---------------------------------------------------------------------------
// Kernel C: dynamic features + attention + output assembly. One block per
// batch element.
// ---------------------------------------------------------------------------
__global__ __launch_bounds__(256) void finalize_kernel(
    const float* __restrict__ job_times, const int* __restrict__ precedence,
    const int* __restrict__ job_state,   const float* __restrict__ jest,
    const float* __restrict__ macut,     const float* __restrict__ mksp,
    const float* __restrict__ Wdyn,      const float* __restrict__ bdyn,
    float* __restrict__ out)
{
    const int b   = blockIdx.x;
    const int tid = threadIdx.x;

    __shared__ float rows[J][MM + 2];  // ordered work per (job, machine)
    __shared__ float twm[MM + 1];
    __shared__ float feats[J][8];
    __shared__ float aw[J];
    __shared__ float fbar[8];

    for (int i = tid; i < J * (MM + 2); i += 256)
        reinterpret_cast<float*>(rows)[i] = 0.f;
    __syncthreads();

    if (tid < J) {
        const int j = tid;
        const int*   pr = &precedence[(b * J + j) * MM];
        const float* jt = &job_times[(b * J + j) * O];
        for (int o = 0; o < O; ++o) rows[j][pr[o]] = jt[o];
    }
    __syncthreads();

    if (tid <= MM) {
        float s = 0.f;
        for (int j = 0; j < J; ++j) s += rows[j][tid];
        twm[tid] = s;
    }
    __syncthreads();

    if (tid < J) {
        const int j  = tid;
        const int js = job_state[b * J + j];
        const float* jt = &job_times[(b * J + j) * O];
        float jpt = (js < O) ? jt[js] : 0.f;
        float jst = jest[b * J + j];
        float twr = 0.f;
        for (int o = js; o < O; ++o) twr += jt[o];
        int   mac = (js < O) ? precedence[(b * J + j) * MM + js] : MM;
        float mu  = (mac < MM) ? macut[b * MM + mac] : 0.f;
        float trm = twm[mac] - mu;
        float cm  = mksp[b];
        float f0 = jpt, f1 = jst, f2 = jst + jpt, f3 = twr, f4 = mu, f5 = trm, f6 = cm;
        feats[j][0] = f0; feats[j][1] = f1; feats[j][2] = f2; feats[j][3] = f3;
        feats[j][4] = f4; feats[j][5] = f5; feats[j][6] = f6; feats[j][7] = 0.f;

        float e = g_cproj;
        e = fmaf(f0, g_wproj[0], e); e = fmaf(f1, g_wproj[1], e);
        e = fmaf(f2, g_wproj[2], e); e = fmaf(f3, g_wproj[3], e);
        e = fmaf(f4, g_wproj[4], e); e = fmaf(f5, g_wproj[5], e);
        e = fmaf(f6, g_wproj[6], e);
        const float* je = &g_je[(b * J + j) * E];
        #pragma unroll 8
        for (int d = 0; d < E; ++d) e = fmaf(je[d], g_hc[d], e);
        aw[j] = e;
    }
    __syncthreads();

    if (tid == 0) {
        float mx = aw[0];
        for (int j = 1; j < J; ++j) mx = fmaxf(mx, aw[j]);
        float sum = 0.f;
        for (int j = 0; j < J; ++j) { float ex = __expf(aw[j] - mx); aw[j] = ex; sum += ex; }
        float inv = __fdividef(1.f, sum);
        for (int j = 0; j < J; ++j) aw[j] *= inv;
    }
    __syncthreads();

    float* ob = out + b * (2 * DD);  // 384 per batch

    if (tid < 8) {
        float s = 0.f;
        for (int j = 0; j < J; ++j) s = fmaf(aw[j], feats[j][tid], s);
        fbar[tid] = s;
    }
    if (tid < DD) ob[tid] = g_hc[tid];
    if (tid >= 64 && tid < 128) {
        const int d = tid - 64;
        float s = 0.f;
        for (int j = 0; j < J; ++j) s = fmaf(aw[j], g_je[(b * J + j) * E + d], s);
        ob[DD + d] = s;
    }
    __syncthreads();
    if (tid < 2 * E) {
        float s = bdyn[tid];
        const float* wd = &Wdyn[tid * 7];
        #pragma unroll
        for (int f = 0; f < 7; ++f) s = fmaf(fbar[f], wd[f], s);
        ob[DD + E + tid] = s;
    }
}

// ---------------------------------------------------------------------------
extern "C" void kernel_launch(void* const* d_in, const int* in_sizes, int n_in,
                              void* d_out, int out_size, void* d_ws, size_t ws_size,
                              hipStream_t stream)
{
    const float* job_times  = (const float*)d_in[0];
    const int*   precedence = (const int*)  d_in[1];
    const int*   job_state  = (const int*)  d_in[2];
    const float* jest       = (const float*)d_in[3];
    const float* macut      = (const float*)d_in[4];
    const float* mksp       = (const float*)d_in[5];
    const float* Wmac       = (const float*)d_in[6];
    const float* bmac       = (const float*)d_in[7];
    const float* Wjt        = (const float*)d_in[8];
    const float* bjt        = (const float*)d_in[9];
    const float* Wih        = (const float*)d_in[10];
    const float* Whh        = (const float*)d_in[11];
    const float* bih        = (const float*)d_in[12];
    const float* bhh        = (const float*)d_in[13];
    const float* Wdyn       = (const float*)d_in[14];
    const float* bdyn       = (const float*)d_in[15];
    // d_in[16] Wih2, d_in[17] Whh2 are mathematically unused (q_star = h = 0)
    const float* bih2       = (const float*)d_in[18];
    const float* bhh2       = (const float*)d_in[19];

    precompute_kernel<<<1, 256, 0, stream>>>(Wmac, bmac, Wjt, bjt, Wih, bih, bhh,
                                             Wdyn, bdyn, bih2, bhh2, job_state);
    lstm_kernel<<<NBATCH, 512, 0, stream>>>(job_times, precedence, job_state, Whh);
    finalize_kernel<<<BS, 256, 0, stream>>>(job_times, precedence, job_state, jest,
                                            macut, mksp, Wdyn, bdyn, (float*)d_out);
}

// Round 7
// 130.546 us; speedup vs baseline: 4.2341x; 1.0324x over previous
//
#include <hip/hip_runtime.h>
#include <hip/hip_bf16.h>
#include <math.h>

#define BS 256
#define J  50
#define O  50
#define MM 50
#define E  64
#define NSEQ (BS*J)     // 12800
#define G4 (4*E)        // 256
#define DD 192          // 3*E
#define NBATCH (NSEQ/32) // 400 batches of 32 sequences
#define KH 88            // padded K row stride: 64 h + pv,jv,1 + pad (176B, 16B-aligned)

typedef _Float16 f16x8 __attribute__((ext_vector_type(8)));
typedef _Float16 f16x4 __attribute__((ext_vector_type(4)));
typedef _Float16 half2v __attribute__((ext_vector_type(2)));
typedef float f32x16 __attribute__((ext_vector_type(16)));

// persistent device scratch (fully rewritten every call)
__device__ float g_u[G4], g_v[G4], g_w[G4];
__device__ float g_h0[E], g_c0[E];
__device__ float g_hc[DD];
__device__ float g_wproj[8];
__device__ float g_cproj;
__device__ float g_je[NSEQ * E];
__device__ int   g_idx[NSEQ];

__device__ __forceinline__ float sigm(float x) {
    return __fdividef(1.f, 1.f + __expf(-x));
}
__device__ __forceinline__ float ftanh(float x) {
    // tanh(x) = 2/(1+exp(-2x)) - 1 ; saturates correctly at both ends
    float e = __expf(-2.f * x);
    return fmaf(2.f, __fdividef(1.f, 1.f + e), -1.f);
}

__device__ __forceinline__ half2v PK(float a, float b) {
#if __has_builtin(__builtin_amdgcn_cvt_pkrtz)
    auto t = __builtin_amdgcn_cvt_pkrtz(a, b);   // __fp16 ext_vector_type(2)
    return __builtin_bit_cast(half2v, t);
#else
    half2v r; r[0] = (_Float16)a; r[1] = (_Float16)b; return r;
#endif
}

// ---------------------------------------------------------------------------
// Kernel A: precompute collapsed input projection (u,v,w), shared first LSTM
// step (h0,c0 — input-independent), Set2Set constant hidden, attention-logit
// projection, and a counting sort of sequences by job_state (51 bins) so the
// MFMA kernel can batch 32 near-equal-length sequences per workgroup.
// ---------------------------------------------------------------------------
__global__ __launch_bounds__(256) void precompute_kernel(
    const float* __restrict__ Wmac, const float* __restrict__ bmac,
    const float* __restrict__ Wjt,  const float* __restrict__ bjt,
    const float* __restrict__ Wih,  const float* __restrict__ bih,
    const float* __restrict__ bhh,
    const float* __restrict__ Wdyn, const float* __restrict__ bdyn,
    const float* __restrict__ bih2, const float* __restrict__ bhh2,
    const int*   __restrict__ job_state)
{
    __shared__ float s_hc[DD];
    __shared__ int cnt51[51], cur51[51];
    const int g = threadIdx.x;  // 0..255

    if (g < 51) cnt51[g] = 0;

    {
        const float* row = &Wih[g * (2 * E)];
        float u = 0.f, v = 0.f, w = 0.f;
        #pragma unroll 8
        for (int e = 0; e < E; ++e) {
            float w0 = row[e], w1 = row[E + e];
            u = fmaf(w0, Wmac[e], u);
            v = fmaf(w1, Wjt[e], v);
            w = fmaf(w0, bmac[e], fmaf(w1, bjt[e], w));
        }
        g_u[g] = u;
        g_v[g] = v;
        g_w[g] = w + bih[g] + bhh[g];
    }

    // Set2Set with q_star=h=c=0: gates = bih2+bhh2 (constant)
    if (g < DD) {
        float gi = bih2[g]          + bhh2[g];
        float gg = bih2[2 * DD + g] + bhh2[2 * DD + g];
        float go = bih2[3 * DD + g] + bhh2[3 * DD + g];
        float c  = sigm(gi) * ftanh(gg);
        float h  = sigm(go) * ftanh(c);
        s_hc[g] = h;
        g_hc[g] = h;
    }
    __syncthreads();

    // shared t=0 LSTM step: inputs are constants (pv = M, jv = 0), h=c=0
    if (g < E) {
        float ai = fmaf((float)MM, g_u[g],         g_w[g]);
        float ag = fmaf((float)MM, g_u[2 * E + g], g_w[2 * E + g]);
        float ao = fmaf((float)MM, g_u[3 * E + g], g_w[3 * E + g]);
        float c0 = sigm(ai) * ftanh(ag);
        float h0 = sigm(ao) * ftanh(c0);
        g_h0[g] = h0;
        g_c0[g] = c0;
    }

    if (g < 8) {
        float s = 0.f;
        if (g < 7) {
            for (int d = 0; d < 2 * E; ++d) s = fmaf(s_hc[E + d], Wdyn[d * 7 + g], s);
        }
        g_wproj[g] = s;
    }
    if (g == 8) {
        float s = 0.f;
        for (int d = 0; d < 2 * E; ++d) s = fmaf(s_hc[E + d], bdyn[d], s);
        g_cproj = s;
    }

    // ---- counting sort by job_state (ascending js = descending length) ----
    for (int s = g; s < NSEQ; s += 256)
        atomicAdd(&cnt51[job_state[s]], 1);
    __syncthreads();
    if (g == 0) {
        int run = 0;
        for (int b2 = 0; b2 < 51; ++b2) { cur51[b2] = run; run += cnt51[b2]; }
    }
    __syncthreads();
    for (int s = g; s < NSEQ; s += 256) {
        int pos = atomicAdd(&cur51[job_state[s]], 1);
        g_idx[pos] = s;
    }
}

// ---------------------------------------------------------------------------
// Kernel B: MFMA-batched LSTM, 4-wave blocks. One 256-thread WG per batch of
// 32 sequences (sorted by length). gates[256x32] = G_ext[256x88]@H_ext[88x32]
// per step; each wave owns TWO 32-row G-tiles (10 MFMA/step, B-frag reused,
// two independent accumulator chains). All per-step inputs (pv,jv) are
// pre-staged into LDS (Hin) at batch start, so the time loop touches no
// global memory. KH=88 padding replaces the XOR swizzle (4-way conflicts,
// simple addressing). ~4 blocks/CU co-resident hide the per-step latency
// chain. Per-lane masking by each sequence's own tmax gives exact semantics.
// ---------------------------------------------------------------------------
__global__ __launch_bounds__(256, 4) void lstm_kernel(
    const float* __restrict__ job_times,   // [BS*J, O]
    const int*   __restrict__ precedence,  // [BS*J, M]
    const int*   __restrict__ job_state,   // [BS*J]
    const float* __restrict__ Whh)         // [256, 64]
{
    __shared__ alignas(16) _Float16 H[32 * KH];
    __shared__ half2v Hin[32][O + 1];      // (pv,jv) per (seq, step t)
    __shared__ int sid_s[32];
    __shared__ int tmx_s[32];
    __shared__ int tmax_sh;

    const int tid  = threadIdx.x;
    const int lane = tid & 63;
    const int wid  = tid >> 6;          // 0..3
    const int n    = lane & 31;         // sequence column (D col = lane&31)
    const int hi   = lane >> 5;

    // ---- loop-invariant A fragments (row-permuted G_ext, f16), 2 tiles ----
    // A row_local = lane&31 -> gate q = rl>>3, unit_local = rl&7
    const int rl = lane & 31;
    f16x8 a[2][5];
    int grow_[2];
    #pragma unroll
    for (int ti = 0; ti < 2; ++ti) {
        const int tile = wid + 4 * ti;                       // 0..7
        const int grow = (rl >> 3) * 64 + 8 * tile + (rl & 7);
        grow_[ti] = grow;
        const float* wr = Whh + grow * 64 + hi * 8;
        #pragma unroll
        for (int kt = 0; kt < 4; ++kt) {
            f16x8 t;
            #pragma unroll
            for (int j = 0; j < 8; ++j) t[j] = (_Float16)wr[kt * 16 + j];
            a[ti][kt] = t;
        }
        f16x8 t;
        #pragma unroll
        for (int j = 0; j < 8; ++j) t[j] = (_Float16)0.f;
        if (hi == 0) {              // k=64,65,66 -> u,v,w columns
            t[0] = (_Float16)g_u[grow];
            t[1] = (_Float16)g_v[grow];
            t[2] = (_Float16)g_w[grow];
        }
        a[ti][4] = t;
    }

    // this lane's units: tile0 -> ub0..ub0+3, tile1 -> ub1..ub1+3
    const int ub0 = 8 * wid + 4 * hi;
    const int ub1 = ub0 + 32;
    float c0r[2][4], h0r[2][4];
    #pragma unroll
    for (int x = 0; x < 4; ++x) {
        c0r[0][x] = g_c0[ub0 + x]; h0r[0][x] = g_h0[ub0 + x];
        c0r[1][x] = g_c0[ub1 + x]; h0r[1][x] = g_h0[ub1 + x];
    }

    const int b = blockIdx.x;           // batch id (longest batches first)

    // ---- batch init ----
    if (tid < 32) {
        int s = g_idx[b * 32 + tid];
        sid_s[tid] = s;
        tmx_s[tid] = O - job_state[s];
    }
    {   // zero H (covers rows 67..87 pad and old data)
        int* Hi = (int*)H;
        for (int i = tid; i < 32 * KH / 2; i += 256) Hi[i] = 0;
    }
    __syncthreads();
    if (tid == 0) {
        int m = 0;
        for (int i = 0; i < 32; ++i) m = max(m, tmx_s[i]);
        tmax_sh = m;
    }
    // stage all per-step inputs into LDS: Hin[n][t] = (pv, jv) at o = O - t
    for (int i = tid; i < 32 * O; i += 256) {
        const int n2 = i / O;
        const int t2 = i % O + 1;      // 1..50
        const int sid2 = sid_s[n2];
        const int o = O - t2;
        float pv = (float)precedence[sid2 * MM + o];
        float jv = job_times[sid2 * O + o];
        Hin[n2][t2] = PK(pv, jv);
    }
    {   // write h0 into H (4 waves x 2 tiles cover all 64 units x 32 cols)
        f16x4 hv0, hv1;
        #pragma unroll
        for (int x = 0; x < 4; ++x) { hv0[x] = (_Float16)h0r[0][x]; hv1[x] = (_Float16)h0r[1][x]; }
        *reinterpret_cast<f16x4*>(&H[n * KH + ub0]) = hv0;
        *reinterpret_cast<f16x4*>(&H[n * KH + ub1]) = hv1;
    }
    if (tid < 32) H[n * KH + 66] = (_Float16)1.f;   // bias row
    __syncthreads();

    const int tmaxM = tmax_sh;
    const int sidn  = sid_s[n];
    const int tmaxn = tmx_s[n];

    if (tid < 32 && tmaxM >= 1) {
        *reinterpret_cast<half2v*>(&H[n * KH + 64]) = Hin[n][1];
    }
    __syncthreads();

    float cr[2][4], hr[2][4];
    #pragma unroll
    for (int x = 0; x < 4; ++x) {
        cr[0][x] = c0r[0][x]; hr[0][x] = h0r[0][x];
        cr[1][x] = c0r[1][x]; hr[1][x] = h0r[1][x];
    }

    // ---- time loop (lockstep over batch; per-lane masked by tmaxn) ----
    for (int t = 1; t <= tmaxM; ++t) {
        // gates = G_ext @ H_ext : 2 independent accumulator chains, B reused
        f32x16 d0, d1;
        #pragma unroll
        for (int j = 0; j < 16; ++j) { d0[j] = 0.f; d1[j] = 0.f; }
        #pragma unroll
        for (int kt = 0; kt < 5; ++kt) {
            const int kb = 16 * kt + 8 * hi;   // k base for this lane
            f16x8 bf = *reinterpret_cast<const f16x8*>(&H[n * KH + kb]);
            d0 = __builtin_amdgcn_mfma_f32_32x32x16_f16(a[0][kt], bf, d0, 0, 0, 0);
            d1 = __builtin_amdgcn_mfma_f32_32x32x16_f16(a[1][kt], bf, d1, 0, 0, 0);
        }

        // activations: lane holds gates i,f,g,o for units ub{0,1}+x, col n
        const bool upd = (t <= tmaxn);
        #pragma unroll
        for (int ti = 0; ti < 2; ++ti) {
            #pragma unroll
            for (int x = 0; x < 4; ++x) {
                const f32x16& d = ti ? d1 : d0;
                float gi = d[x], gf = d[4 + x], gg = d[8 + x], go = d[12 + x];
                float si = sigm(gi), sf = sigm(gf), so = sigm(go);
                float tg = ftanh(gg);
                float cn = fmaf(sf, cr[ti][x], si * tg);
                float hn = so * ftanh(cn);
                if (upd) { cr[ti][x] = cn; hr[ti][x] = hn; }
            }
        }
        __syncthreads();               // all B-fragment reads of step t done
        if (upd) {
            f16x4 hv0, hv1;
            #pragma unroll
            for (int x = 0; x < 4; ++x) { hv0[x] = (_Float16)hr[0][x]; hv1[x] = (_Float16)hr[1][x]; }
            *reinterpret_cast<f16x4*>(&H[n * KH + ub0]) = hv0;
            *reinterpret_cast<f16x4*>(&H[n * KH + ub1]) = hv1;
        }
        if (tid < 32 && t < tmaxM) {
            *reinterpret_cast<half2v*>(&H[n * KH + 64]) = Hin[n][t + 1];
        }
        __syncthreads();               // step t+1 inputs visible
    }

    // ---- write final hidden (f32) ----
    {
        float4 v0 = make_float4(hr[0][0], hr[0][1], hr[0][2], hr[0][3]);
        float4 v1 = make_float4(hr[1][0], hr[1][1], hr[1][2], hr[1][3]);
        *reinterpret_cast<float4*>(&g_je[sidn * E + ub0]) = v0;
        *reinterpret_cast<float4*>(&g_je[sidn * E + ub1]) = v1;
    }
}

// ---------------------------------------------------------------------------
// Kernel C: dynamic features + attention + output assembly. One block per
// batch element.
// ---------------------------------------------------------------------------
__global__ __launch_bounds__(256) void finalize_kernel(
    const float* __restrict__ job_times, const int* __restrict__ precedence,
    const int* __restrict__ job_state,   const float* __restrict__ jest,
    const float* __restrict__ macut,     const float* __restrict__ mksp,
    const float* __restrict__ Wdyn,      const float* __restrict__ bdyn,
    float* __restrict__ out)
{
    const int b   = blockIdx.x;
    const int tid = threadIdx.x;

    __shared__ float rows[J][MM + 2];  // ordered work per (job, machine)
    __shared__ float twm[MM + 1];
    __shared__ float feats[J][8];
    __shared__ float aw[J];
    __shared__ float fbar[8];

    for (int i = tid; i < J * (MM + 2); i += 256)
        reinterpret_cast<float*>(rows)[i] = 0.f;
    __syncthreads();

    if (tid < J) {
        const int j = tid;
        const int*   pr = &precedence[(b * J + j) * MM];
        const float* jt = &job_times[(b * J + j) * O];
        for (int o = 0; o < O; ++o) rows[j][pr[o]] = jt[o];
    }
    __syncthreads();

    if (tid <= MM) {
        float s = 0.f;
        for (int j = 0; j < J; ++j) s += rows[j][tid];
        twm[tid] = s;
    }
    __syncthreads();

    if (tid < J) {
        const int j  = tid;
        const int js = job_state[b * J + j];
        const float* jt = &job_times[(b * J + j) * O];
        float jpt = (js < O) ? jt[js] : 0.f;
        float jst = jest[b * J + j];
        float twr = 0.f;
        for (int o = js; o < O; ++o) twr += jt[o];
        int   mac = (js < O) ? precedence[(b * J + j) * MM + js] : MM;
        float mu  = (mac < MM) ? macut[b * MM + mac] : 0.f;
        float trm = twm[mac] - mu;
        float cm  = mksp[b];
        float f0 = jpt, f1 = jst, f2 = jst + jpt, f3 = twr, f4 = mu, f5 = trm, f6 = cm;
        feats[j][0] = f0; feats[j][1] = f1; feats[j][2] = f2; feats[j][3] = f3;
        feats[j][4] = f4; feats[j][5] = f5; feats[j][6] = f6; feats[j][7] = 0.f;

        float e = g_cproj;
        e = fmaf(f0, g_wproj[0], e); e = fmaf(f1, g_wproj[1], e);
        e = fmaf(f2, g_wproj[2], e); e = fmaf(f3, g_wproj[3], e);
        e = fmaf(f4, g_wproj[4], e); e = fmaf(f5, g_wproj[5], e);
        e = fmaf(f6, g_wproj[6], e);
        const float* je = &g_je[(b * J + j) * E];
        #pragma unroll 8
        for (int d = 0; d < E; ++d) e = fmaf(je[d], g_hc[d], e);
        aw[j] = e;
    }
    __syncthreads();

    if (tid == 0) {
        float mx = aw[0];
        for (int j = 1; j < J; ++j) mx = fmaxf(mx, aw[j]);
        float sum = 0.f;
        for (int j = 0; j < J; ++j) { float ex = __expf(aw[j] - mx); aw[j] = ex; sum += ex; }
        float inv = __fdividef(1.f, sum);
        for (int j = 0; j < J; ++j) aw[j] *= inv;
    }
    __syncthreads();

    float* ob = out + b * (2 * DD);  // 384 per batch

    if (tid < 8) {
        float s = 0.f;
        for (int j = 0; j < J; ++j) s = fmaf(aw[j], feats[j][tid], s);
        fbar[tid] = s;
    }
    if (tid < DD) ob[tid] = g_hc[tid];
    if (tid >= 64 && tid < 128) {
        const int d = tid - 64;
        float s = 0.f;
        for (int j = 0; j < J; ++j) s = fmaf(aw[j], g_je[(b * J + j) * E + d], s);
        ob[DD + d] = s;
    }
    __syncthreads();
    if (tid < 2 * E) {
        float s = bdyn[tid];
        const float* wd = &Wdyn[tid * 7];
        #pragma unroll
        for (int f = 0; f < 7; ++f) s = fmaf(fbar[f], wd[f], s);
        ob[DD + E + tid] = s;
    }
}

// ---------------------------------------------------------------------------
extern "C" void kernel_launch(void* const* d_in, const int* in_sizes, int n_in,
                              void* d_out, int out_size, void* d_ws, size_t ws_size,
                              hipStream_t stream)
{
    const float* job_times  = (const float*)d_in[0];
    const int*   precedence = (const int*)  d_in[1];
    const int*   job_state  = (const int*)  d_in[2];
    const float* jest       = (const float*)d_in[3];
    const float* macut      = (const float*)d_in[4];
    const float* mksp       = (const float*)d_in[5];
    const float* Wmac       = (const float*)d_in[6];
    const float* bmac       = (const float*)d_in[7];
    const float* Wjt        = (const float*)d_in[8];
    const float* bjt        = (const float*)d_in[9];
    const float* Wih        = (const float*)d_in[10];
    const float* Whh        = (const float*)d_in[11];
    const float* bih        = (const float*)d_in[12];
    const float* bhh        = (const float*)d_in[13];
    const float* Wdyn       = (const float*)d_in[14];
    const float* bdyn       = (const float*)d_in[15];
    // d_in[16] Wih2, d_in[17] Whh2 are mathematically unused (q_star = h = 0)
    const float* bih2       = (const float*)d_in[18];
    const float* bhh2       = (const float*)d_in[19];

    precompute_kernel<<<1, 256, 0, stream>>>(Wmac, bmac, Wjt, bjt, Wih, bih, bhh,
                                             Wdyn, bdyn, bih2, bhh2, job_state);
    lstm_kernel<<<NBATCH, 256, 0, stream>>>(job_times, precedence, job_state, Whh);
    finalize_kernel<<<BS, 256, 0, stream>>>(job_times, precedence, job_state, jest,
                                            macut, mksp, Wdyn, bdyn, (float*)d_out);
}